// Round 1
// baseline (200.569 us; speedup 1.0000x reference)
//
#include <hip/hip_runtime.h>

// Geometry: G=256 graphs x 64 nodes, H=8 heads x D=8, IN_DIM=EDGE_DIM=64
// EF = 1048576 full edges, ES = 262144 sparse edges.
// edge f = b*4096 + i*64 + j  (src=i, dst=j); sparse s = b*1024 + j*16 + k, i=(j+1+k)&63.

__global__ __launch_bounds__(512, 1) void attn_kernel(
    const float* __restrict__ h,
    const float* __restrict__ e,
    const float* __restrict__ adj2,
    const float* __restrict__ rel,
    const float* __restrict__ Wq, const float* __restrict__ bq,
    const float* __restrict__ Wk, const float* __restrict__ bk,
    const float* __restrict__ Wv, const float* __restrict__ bv,
    const float* __restrict__ Wpe, const float* __restrict__ bpe,
    const float* __restrict__ Wo, const float* __restrict__ bo,
    float* __restrict__ h_out,
    float* __restrict__ scsp)   // [ES rows, stride 64 floats, cols 0..7] (= e_out region)
{
    __shared__ float shQ[64 * 68];
    __shared__ float shK[64 * 68];
    __shared__ float shV[64 * 68];
    __shared__ float shPE[1024 * 8];

    const int b    = blockIdx.x;
    const int t    = threadIdx.x;
    const int lane = t & 63;
    const int wu   = __builtin_amdgcn_readfirstlane(t >> 6);  // wave id 0..7, uniform

    // ---- P0: Q,K,V = h @ W^T + b. lane = node row; wave wu owns cols [8wu,8wu+8).
    {
        const float* hrow = h + (size_t)(b * 64 + lane) * 64;
        float accQ[8], accK[8], accV[8];
        #pragma unroll
        for (int cc = 0; cc < 8; ++cc) {
            const int c = wu * 8 + cc;
            accQ[cc] = bq[c]; accK[cc] = bk[c]; accV[cc] = bv[c];
        }
        #pragma unroll
        for (int k0 = 0; k0 < 4; ++k0) {
            float hv[16];
            #pragma unroll
            for (int u = 0; u < 4; ++u) {
                const float4 x = ((const float4*)hrow)[k0 * 4 + u];
                hv[u*4+0] = x.x; hv[u*4+1] = x.y; hv[u*4+2] = x.z; hv[u*4+3] = x.w;
            }
            #pragma unroll
            for (int cc = 0; cc < 8; ++cc) {
                const int c = wu * 8 + cc;
                const float* wq  = Wq + c * 64 + k0 * 16;   // wave-uniform -> s_load
                const float* wk  = Wk + c * 64 + k0 * 16;
                const float* wvp = Wv + c * 64 + k0 * 16;
                #pragma unroll
                for (int k = 0; k < 16; ++k) {
                    accQ[cc] = fmaf(hv[k], wq[k],  accQ[cc]);
                    accK[cc] = fmaf(hv[k], wk[k],  accK[cc]);
                    accV[cc] = fmaf(hv[k], wvp[k], accV[cc]);
                }
            }
        }
        float* qp = &shQ[lane * 68 + wu * 8];
        *(float4*)(qp)     = make_float4(accQ[0], accQ[1], accQ[2], accQ[3]);
        *(float4*)(qp + 4) = make_float4(accQ[4], accQ[5], accQ[6], accQ[7]);
        float* kp = &shK[lane * 68 + wu * 8];
        *(float4*)(kp)     = make_float4(accK[0], accK[1], accK[2], accK[3]);
        *(float4*)(kp + 4) = make_float4(accK[4], accK[5], accK[6], accK[7]);
        float* vp = &shV[lane * 68 + wu * 8];
        *(float4*)(vp)     = make_float4(accV[0], accV[1], accV[2], accV[3]);
        *(float4*)(vp + 4) = make_float4(accV[4], accV[5], accV[6], accV[7]);
    }
    __syncthreads();

    // ---- P1: per-thread Q fragment, thread = (j = t>>3, hh = t&7)
    const int j  = t >> 3;
    const int hh = t & 7;
    float q[8];
    {
        const float* qp = &shQ[j * 68 + hh * 8];
        const float4 a = *(const float4*)qp;
        const float4 c = *(const float4*)(qp + 4);
        q[0]=a.x; q[1]=a.y; q[2]=a.z; q[3]=a.w;
        q[4]=c.x; q[5]=c.y; q[6]=c.z; q[7]=c.w;
    }

    // ---- P2: proj_e = e @ Wpe^T + bpe for this block's 1024 sparse-edge rows
    {
        const float* eB = e + (size_t)b * 1024 * 64;
        #pragma unroll
        for (int pp = 0; pp < 2; ++pp) {
            const int p   = wu + pp * 8;        // pass 0..15
            const int row = p * 64 + lane;      // sparse row within block
            const float* erow = eB + row * 64;
            float acc[8];
            #pragma unroll
            for (int h2 = 0; h2 < 8; ++h2) acc[h2] = bpe[h2];
            #pragma unroll
            for (int k0 = 0; k0 < 4; ++k0) {
                float ev[16];
                #pragma unroll
                for (int u = 0; u < 4; ++u) {
                    const float4 x = ((const float4*)erow)[k0 * 4 + u];
                    ev[u*4+0] = x.x; ev[u*4+1] = x.y; ev[u*4+2] = x.z; ev[u*4+3] = x.w;
                }
                #pragma unroll
                for (int h2 = 0; h2 < 8; ++h2) {
                    const float* wp = Wpe + h2 * 64 + k0 * 16;  // uniform -> s_load
                    #pragma unroll
                    for (int k = 0; k < 16; ++k)
                        acc[h2] = fmaf(ev[k], wp[k], acc[h2]);
                }
            }
            float* p0 = &shPE[row * 8];
            *(float4*)(p0)     = make_float4(acc[0], acc[1], acc[2], acc[3]);
            *(float4*)(p0 + 4) = make_float4(acc[4], acc[5], acc[6], acc[7]);
        }
    }
    __syncthreads();

    // ---- P3: edge scores + online softmax (no max needed: logits clipped to [-5,5])
    float den = 0.f;
    float wv[8] = {0.f,0.f,0.f,0.f,0.f,0.f,0.f,0.f};
    const float* adjB = adj2 + (size_t)b * 4096;
    const float* relB = rel  + (size_t)b * 4096 * 8;
    float* scspB = scsp + (size_t)b * 1024 * 64;
    const float inv_scale = 0.35355339059327379f;  // 1/sqrt(8)
    #pragma unroll 4
    for (int i = 0; i < 64; ++i) {
        const float4 kA = *(const float4*)&shK[i * 68 + hh * 8];
        const float4 kB = *(const float4*)&shK[i * 68 + hh * 8 + 4];
        float s;
        s = kA.x * q[0];
        s = fmaf(kA.y, q[1], s); s = fmaf(kA.z, q[2], s); s = fmaf(kA.w, q[3], s);
        s = fmaf(kB.x, q[4], s); s = fmaf(kB.y, q[5], s); s = fmaf(kB.z, q[6], s);
        s = fmaf(kB.w, q[7], s);
        const int eidx = i * 64 + j;
        const float a2 = adjB[eidx];
        const float rp = relB[eidx * 8 + hh];
        s = fmaf(s * inv_scale, a2, rp);          // score (pre proj_e, unclipped)
        const int kidx = (i - j - 1) & 63;
        if (kidx < 16) {                          // sparse edge (i -> j)
            const int srow = j * 16 + kidx;
            scspB[srow * 64 + hh] = s;            // sc_sp for e_out kernel
            s += shPE[srow * 8 + hh];             // softmax sees sc_sp + proj_e
        }
        s = fminf(fmaxf(s, -5.f), 5.f);
        const float ex = __expf(s);
        den += ex;
        const float4 vA = *(const float4*)&shV[i * 68 + hh * 8];
        const float4 vB = *(const float4*)&shV[i * 68 + hh * 8 + 4];
        wv[0] = fmaf(ex, vA.x, wv[0]); wv[1] = fmaf(ex, vA.y, wv[1]);
        wv[2] = fmaf(ex, vA.z, wv[2]); wv[3] = fmaf(ex, vA.w, wv[3]);
        wv[4] = fmaf(ex, vB.x, wv[4]); wv[5] = fmaf(ex, vB.y, wv[5]);
        wv[6] = fmaf(ex, vB.z, wv[6]); wv[7] = fmaf(ex, vB.w, wv[7]);
    }
    {
        const float id = 1.f / den;
        float* wp = &shQ[j * 68 + hh * 8];        // shQ reused as wV matrix
        *(float4*)(wp)     = make_float4(wv[0]*id, wv[1]*id, wv[2]*id, wv[3]*id);
        *(float4*)(wp + 4) = make_float4(wv[4]*id, wv[5]*id, wv[6]*id, wv[7]*id);
    }
    __syncthreads();

    // ---- P5: h_out = wV @ Wo^T + bo  (lane = row, wave owns 8 cols)
    {
        const float* wrow = &shQ[lane * 68];
        float acc[8];
        #pragma unroll
        for (int cc = 0; cc < 8; ++cc) acc[cc] = bo[wu * 8 + cc];
        #pragma unroll
        for (int k0 = 0; k0 < 4; ++k0) {
            float tv[16];
            #pragma unroll
            for (int u = 0; u < 4; ++u) {
                const float4 x = *(const float4*)(wrow + k0 * 16 + u * 4);
                tv[u*4+0] = x.x; tv[u*4+1] = x.y; tv[u*4+2] = x.z; tv[u*4+3] = x.w;
            }
            #pragma unroll
            for (int cc = 0; cc < 8; ++cc) {
                const float* wo = Wo + (wu * 8 + cc) * 64 + k0 * 16;  // uniform
                #pragma unroll
                for (int k = 0; k < 16; ++k)
                    acc[cc] = fmaf(tv[k], wo[k], acc[cc]);
            }
        }
        float* orow = h_out + (size_t)(b * 64 + lane) * 64 + wu * 8;
        *(float4*)(orow)     = make_float4(acc[0], acc[1], acc[2], acc[3]);
        *(float4*)(orow + 4) = make_float4(acc[4], acc[5], acc[6], acc[7]);
    }
}

// e_out = (sc_sp @ Wap^T + bap + e) @ Woe^T + boe.  One thread per edge row.
// Pure-register: t-row in 64 VGPRs, weights streamed through SGPRs (uniform idx).
__global__ __launch_bounds__(256, 1) void eout_kernel(
    const float* __restrict__ e,
    const float* __restrict__ scsp,   // stride-64 rows, cols 0..7 (inside e_out region)
    const float* __restrict__ Wap, const float* __restrict__ bap,
    const float* __restrict__ Woe, const float* __restrict__ boe,
    float* __restrict__ e_out)
{
    const int row = blockIdx.x * 256 + threadIdx.x;    // 0..ES-1
    const float* erow = e + (size_t)row * 64;

    float trow[64];
    #pragma unroll
    for (int v = 0; v < 16; ++v) {
        const float4 x = ((const float4*)erow)[v];
        trow[v*4+0] = x.x; trow[v*4+1] = x.y; trow[v*4+2] = x.z; trow[v*4+3] = x.w;
    }
    float sc[8];
    {
        const float* srow = scsp + (size_t)row * 64;
        const float4 a = *(const float4*)srow;
        const float4 c = *(const float4*)(srow + 4);
        sc[0]=a.x; sc[1]=a.y; sc[2]=a.z; sc[3]=a.w;
        sc[4]=c.x; sc[5]=c.y; sc[6]=c.z; sc[7]=c.w;
    }
    // t = e + bap + sc_sp @ Wap^T
    #pragma unroll
    for (int c = 0; c < 64; ++c) {
        float acc = trow[c] + bap[c];
        #pragma unroll
        for (int h2 = 0; h2 < 8; ++h2)
            acc = fmaf(sc[h2], Wap[c * 8 + h2], acc);   // uniform -> s_load
        trow[c] = acc;
    }
    // e_out = t @ Woe^T + boe, 16 output cols at a time
    float* orow = e_out + (size_t)row * 64;
    for (int cc4 = 0; cc4 < 4; ++cc4) {                 // runtime loop: code size
        float acc[16];
        #pragma unroll
        for (int u = 0; u < 16; ++u) acc[u] = boe[cc4 * 16 + u];
        #pragma unroll
        for (int u = 0; u < 16; ++u) {
            const float* wr = Woe + (cc4 * 16 + u) * 64;  // uniform row base
            #pragma unroll
            for (int k = 0; k < 64; ++k)
                acc[u] = fmaf(trow[k], wr[k], acc[u]);
        }
        #pragma unroll
        for (int u = 0; u < 4; ++u)
            *(float4*)&orow[cc4 * 16 + u * 4] =
                make_float4(acc[u*4+0], acc[u*4+1], acc[u*4+2], acc[u*4+3]);
    }
}

extern "C" void kernel_launch(void* const* d_in, const int* in_sizes, int n_in,
                              void* d_out, int out_size, void* d_ws, size_t ws_size,
                              hipStream_t stream) {
    const float* h    = (const float*)d_in[0];
    const float* e    = (const float*)d_in[1];
    const float* adj2 = (const float*)d_in[2];
    const float* rel  = (const float*)d_in[3];
    const float* Wq   = (const float*)d_in[4];  const float* bq  = (const float*)d_in[5];
    const float* Wk   = (const float*)d_in[6];  const float* bk  = (const float*)d_in[7];
    const float* Wv   = (const float*)d_in[8];  const float* bv  = (const float*)d_in[9];
    const float* Wpe  = (const float*)d_in[10]; const float* bpe = (const float*)d_in[11];
    const float* Wap  = (const float*)d_in[12]; const float* bap = (const float*)d_in[13];
    const float* Wo   = (const float*)d_in[14]; const float* bo  = (const float*)d_in[15];
    const float* Woe  = (const float*)d_in[16]; const float* boe = (const float*)d_in[17];

    float* out  = (float*)d_out;
    float* hout = out;                    // [16384*64]
    float* eout = out + 16384 * 64;       // [262144*64]
    float* scsp = eout;                   // sc_sp staged at [row*64 + h] inside e_out

    attn_kernel<<<dim3(256), dim3(512), 0, stream>>>(
        h, e, adj2, rel, Wq, bq, Wk, bk, Wv, bv, Wpe, bpe, Wo, bo, hout, scsp);
    eout_kernel<<<dim3(1024), dim3(256), 0, stream>>>(
        e, scsp, Wap, bap, Woe, boe, eout);
}